// Round 1
// baseline (182.347 us; speedup 1.0000x reference)
//
#include <hip/hip_runtime.h>

// Layout constants for activation (32, 16, 224, 224) fp32
#define HW      224
#define PLANE   50176            // 224*224
#define NSTRIDE 802816           // 16*PLANE

// Work partition (all boundaries are multiples of 256 -> uniform waves):
// A: ch 0..3, one float4/thread         : 32*4*PLANE/4   = 1,605,632
// B: ch 4..7 (2x2), one 2x4 region/thr  : 32*4*112*56    =   802,816
// C: ch 8..11 (4x4), one block/thr      : 32*4*56*56     =   401,408
// D: ch 12..15 (3x3), one block/thr     : 32*4*75*75     =   720,000
constexpr int A_END = 1605632;
constexpr int B_END = A_END + 802816;   // 2,408,448
constexpr int C_END = B_END + 401408;   // 2,809,856
constexpr int TOTAL = C_END + 720000;   // 3,529,856

__global__ __launch_bounds__(256) void blockrelu_kernel(
    const float* __restrict__ in, float* __restrict__ out) {
  const int tid = blockIdx.x * 256 + threadIdx.x;
  if (tid >= TOTAL) return;

  if (tid < A_END) {
    // Channels 0..3 are contiguous per n (4 planes = 50176 float4s).
    int n = tid / PLANE;          // PLANE float4s per n-chunk
    int r = tid - n * PLANE;      // float4 index inside the 4-plane chunk
    int c = r / 12544;            // 0..3 (12544 float4s per plane)
    long off = (long)n * NSTRIDE + (long)r * 4;
    float4 v = *(const float4*)(in + off);
    if (c >= 2) {                 // 1x1 blocks: sign(x) mask == ReLU (x>=0 keeps)
      v.x = (v.x >= 0.f) ? v.x : 0.f;
      v.y = (v.y >= 0.f) ? v.y : 0.f;
      v.z = (v.z >= 0.f) ? v.z : 0.f;
      v.w = (v.w >= 0.f) ? v.w : 0.f;
    }
    *(float4*)(out + off) = v;
  } else if (tid < B_END) {
    // 2x2 blocks, thread handles a 2-row x 4-col region (two blocks)
    int u = tid - A_END;
    int n = u / 25088;            // 4 ch * 6272 regions
    int v2 = u - n * 25088;
    int c = 4 + v2 / 6272;
    int w2 = v2 % 6272;
    int brow = w2 / 56;           // 112 block-rows
    int rcol = w2 - brow * 56;    // 56 regions of width 4
    long base = (long)n * NSTRIDE + (long)c * PLANE + (long)(2 * brow) * HW + 4 * rcol;
    float4 a = *(const float4*)(in + base);
    float4 b = *(const float4*)(in + base + HW);
    // reference sum order: row-major within block
    float s0 = ((a.x + a.y) + b.x) + b.y;
    float s1 = ((a.z + a.w) + b.z) + b.w;
    if (s0 < 0.f) { a.x = 0.f; a.y = 0.f; b.x = 0.f; b.y = 0.f; }
    if (s1 < 0.f) { a.z = 0.f; a.w = 0.f; b.z = 0.f; b.w = 0.f; }
    *(float4*)(out + base) = a;
    *(float4*)(out + base + HW) = b;
  } else if (tid < C_END) {
    // 4x4 blocks, one block per thread
    int u = tid - B_END;
    int n = u / 12544;            // 4 ch * 3136 blocks
    int v2 = u - n * 12544;
    int c = 8 + v2 / 3136;
    int w2 = v2 % 3136;
    int by = w2 / 56;
    int bx = w2 - by * 56;
    long base = (long)n * NSTRIDE + (long)c * PLANE + (long)(4 * by) * HW + 4 * bx;
    float4 r0 = *(const float4*)(in + base);
    float4 r1 = *(const float4*)(in + base + HW);
    float4 r2 = *(const float4*)(in + base + 2 * HW);
    float4 r3 = *(const float4*)(in + base + 3 * HW);
    float s = r0.x; s += r0.y; s += r0.z; s += r0.w;
    s += r1.x; s += r1.y; s += r1.z; s += r1.w;
    s += r2.x; s += r2.y; s += r2.z; s += r2.w;
    s += r3.x; s += r3.y; s += r3.z; s += r3.w;
    if (s < 0.f) {
      r0 = make_float4(0.f, 0.f, 0.f, 0.f);
      r1 = r0; r2 = r0; r3 = r0;
    }
    *(float4*)(out + base) = r0;
    *(float4*)(out + base + HW) = r1;
    *(float4*)(out + base + 2 * HW) = r2;
    *(float4*)(out + base + 3 * HW) = r3;
  } else {
    // 3x3 blocks (H,W padded 224->225 with zeros), one block per thread
    int u = tid - C_END;
    int n = u / 22500;            // 4 ch * 5625 blocks
    int v2 = u - n * 22500;
    int c = 12 + v2 / 5625;
    int w2 = v2 % 5625;
    int by = w2 / 75;
    int bx = w2 - by * 75;
    int h0 = 3 * by, w0 = 3 * bx;
    int hmax = (224 - h0 < 3) ? (224 - h0) : 3;
    int wmax = (224 - w0 < 3) ? (224 - w0) : 3;
    long base = (long)n * NSTRIDE + (long)c * PLANE + (long)h0 * HW + w0;
    float vals[3][3];
    float s = 0.f;
    // reference sum order: row-major; padded (missing) entries contribute 0
    #pragma unroll
    for (int i = 0; i < 3; ++i) {
      #pragma unroll
      for (int j = 0; j < 3; ++j) {
        float x = 0.f;
        if (i < hmax && j < wmax) x = in[base + i * HW + j];
        vals[i][j] = x;
        s += x;
      }
    }
    const float keep = (s >= 0.f) ? 1.f : 0.f;
    #pragma unroll
    for (int i = 0; i < 3; ++i) {
      #pragma unroll
      for (int j = 0; j < 3; ++j) {
        if (i < hmax && j < wmax) out[base + i * HW + j] = keep * vals[i][j];
      }
    }
  }
}

extern "C" void kernel_launch(void* const* d_in, const int* in_sizes, int n_in,
                              void* d_out, int out_size, void* d_ws, size_t ws_size,
                              hipStream_t stream) {
  const float* act = (const float*)d_in[0];
  float* out = (float*)d_out;
  const int grid = (TOTAL + 255) / 256;   // 13,789 blocks
  blockrelu_kernel<<<grid, 256, 0, stream>>>(act, out);
}

// Round 2
// 181.804 us; speedup vs baseline: 1.0030x; 1.0030x over previous
//
#include <hip/hip_runtime.h>

// Layout constants for activation (32, 16, 224, 224) fp32
#define HW      224
#define PLANE   50176            // 224*224
#define NSTRIDE 802816           // 16*PLANE

// Grid partition (branch on blockIdx.x -> workgroup-uniform):
// A: ch 0..3, one float4/thread          : 6272 blocks (1,605,632 threads)
// B: ch 4..7 (2x2), one 2x4 region/thr   : 3136 blocks
// C: ch 8..11 (4x4), one block/thr       : 1568 blocks
// D: ch 12..15 (3x3), LDS strip scheme   : 3200 blocks (128 planes x 25 strips)
constexpr int A_BLOCKS = 6272;
constexpr int AB   = A_BLOCKS;            // 6272
constexpr int ABC  = AB + 3136;           // 9408
constexpr int ABCD = ABC + 1568;          // 10976
constexpr int TOTAL_BLOCKS = ABCD + 3200; // 14176

__global__ __launch_bounds__(256) void blockrelu_kernel(
    const float* __restrict__ in, float* __restrict__ out) {
  const int bid = blockIdx.x;
  const int t = threadIdx.x;

  // LDS for section D (allocated for all blocks; 9.2 KB, not the occupancy limiter)
  __shared__ float tile[9][228];   // 9 rows x 224 cols, padded to 228 (zero pad col 224)
  __shared__ float maskL[3][76];   // 3 block-rows x 75 block-cols

  if (bid < AB) {
    // Channels 0..3: copy (ch 0-1) or elementwise ReLU (ch 2-3). One float4/thread.
    int tid = bid * 256 + t;      // float4 index; 50176 float4s per n (4 planes)
    int n = tid / PLANE;
    int r = tid - n * PLANE;
    int c = r / 12544;            // 0..3
    long off = (long)n * NSTRIDE + (long)r * 4;
    float4 v = *(const float4*)(in + off);
    if (c >= 2) {
      v.x = (v.x >= 0.f) ? v.x : 0.f;
      v.y = (v.y >= 0.f) ? v.y : 0.f;
      v.z = (v.z >= 0.f) ? v.z : 0.f;
      v.w = (v.w >= 0.f) ? v.w : 0.f;
    }
    *(float4*)(out + off) = v;
  } else if (bid < ABC) {
    // 2x2 blocks: thread handles a 2-row x 4-col region (two blocks)
    int u = (bid - AB) * 256 + t;
    int n = u / 25088;
    int v2 = u - n * 25088;
    int c = 4 + v2 / 6272;
    int w2 = v2 % 6272;
    int brow = w2 / 56;
    int rcol = w2 - brow * 56;
    long base = (long)n * NSTRIDE + (long)c * PLANE + (long)(2 * brow) * HW + 4 * rcol;
    float4 a = *(const float4*)(in + base);
    float4 b = *(const float4*)(in + base + HW);
    float s0 = ((a.x + a.y) + b.x) + b.y;   // row-major order (matches XLA exactly, R1)
    float s1 = ((a.z + a.w) + b.z) + b.w;
    if (s0 < 0.f) { a.x = 0.f; a.y = 0.f; b.x = 0.f; b.y = 0.f; }
    if (s1 < 0.f) { a.z = 0.f; a.w = 0.f; b.z = 0.f; b.w = 0.f; }
    *(float4*)(out + base) = a;
    *(float4*)(out + base + HW) = b;
  } else if (bid < ABCD) {
    // 4x4 blocks: one block per thread
    int u = (bid - ABC) * 256 + t;
    int n = u / 12544;
    int v2 = u - n * 12544;
    int c = 8 + v2 / 3136;
    int w2 = v2 % 3136;
    int by = w2 / 56;
    int bx = w2 - by * 56;
    long base = (long)n * NSTRIDE + (long)c * PLANE + (long)(4 * by) * HW + 4 * bx;
    float4 r0 = *(const float4*)(in + base);
    float4 r1 = *(const float4*)(in + base + HW);
    float4 r2 = *(const float4*)(in + base + 2 * HW);
    float4 r3 = *(const float4*)(in + base + 3 * HW);
    float s = r0.x; s += r0.y; s += r0.z; s += r0.w;
    s += r1.x; s += r1.y; s += r1.z; s += r1.w;
    s += r2.x; s += r2.y; s += r2.z; s += r2.w;
    s += r3.x; s += r3.y; s += r3.z; s += r3.w;
    if (s < 0.f) {
      r0 = make_float4(0.f, 0.f, 0.f, 0.f);
      r1 = r0; r2 = r0; r3 = r0;
    }
    *(float4*)(out + base) = r0;
    *(float4*)(out + base + HW) = r1;
    *(float4*)(out + base + 2 * HW) = r2;
    *(float4*)(out + base + 3 * HW) = r3;
  } else {
    // 3x3 blocks via LDS strips: one workgroup per 3 block-rows (9 image rows)
    // of one (n,c) plane. Global traffic fully float4-coalesced.
    int wg = bid - ABCD;          // 0..3199
    int p = wg / 25;              // plane 0..127
    int sg = wg - p * 25;         // strip-group 0..24
    int n = p >> 2;
    int c = 12 + (p & 3);
    int h0 = sg * 9;              // first image row of strip
    int rows = (224 - h0 >= 9) ? 9 : (224 - h0);   // 9, or 8 for sg==24
    long pbase = (long)n * NSTRIDE + (long)c * PLANE;

    // Zero LDS tile (pad cols 224..227 and pad row must be exact zeros)
    for (int i = t; i < 9 * 228; i += 256) ((float*)tile)[i] = 0.f;
    __syncthreads();

    // Coalesced cooperative load: rows*56 float4s
    const int nvec = rows * 56;
    for (int idx = t; idx < nvec; idx += 256) {
      int r = idx / 56;
      int q = idx - r * 56;
      float4 v = *(const float4*)(in + pbase + (long)(h0 + r) * HW + q * 4);
      *(float4*)&tile[r][q * 4] = v;
    }
    __syncthreads();

    // 225 block sums (3 block-rows x 75 block-cols), row-major order.
    // Pad entries are exact 0.f -> adding them is bit-exact vs skipping.
    if (t < 225) {
      int br = t / 75;
      int bx = t - br * 75;
      int r0 = br * 3, c0 = bx * 3;   // stride-3 LDS reads: gcd(3,32)=1, conflict-free
      float s = 0.f;
      #pragma unroll
      for (int i = 0; i < 3; ++i)
        #pragma unroll
        for (int j = 0; j < 3; ++j)
          s += tile[r0 + i][c0 + j];
      maskL[br][bx] = (s >= 0.f) ? 1.f : 0.f;
    }
    __syncthreads();

    // Apply mask, coalesced float4 store
    for (int idx = t; idx < nvec; idx += 256) {
      int r = idx / 56;
      int q = idx - r * 56;
      int col = q * 4;
      float4 v = *(const float4*)&tile[r][col];
      int br = r / 3;
      v.x *= maskL[br][(col    ) / 3];
      v.y *= maskL[br][(col + 1) / 3];
      v.z *= maskL[br][(col + 2) / 3];
      v.w *= maskL[br][(col + 3) / 3];
      *(float4*)(out + pbase + (long)(h0 + r) * HW + col) = v;
    }
  }
}

extern "C" void kernel_launch(void* const* d_in, const int* in_sizes, int n_in,
                              void* d_out, int out_size, void* d_ws, size_t ws_size,
                              hipStream_t stream) {
  const float* act = (const float*)d_in[0];
  float* out = (float*)d_out;
  blockrelu_kernel<<<TOTAL_BLOCKS, 256, 0, stream>>>(act, out);
}